// Round 2
// 551.277 us; speedup vs baseline: 1.2477x; 1.2477x over previous
//
#include <hip/hip_runtime.h>

// ---------------------------------------------------------------------------
// MultiHead_BlockAttention: out[b,s,h*512+d] = softmax(Q Kt) V  per (h,b)
//   Q = x@wq, K = x@wk, V = x@wv ; head h = cols [h*512,(h+1)*512)
// Trick: logits = X (Wq Wk^T) X^T  -> precompute M' = Wk Wq^T per head.
// Precision: bf16 hi/lo split (3 MFMAs) on the logit path; plain bf16 for V/P.
// R1: the two big split GEMMs (T, logits) moved to gemm256 — 256x256 tile,
//     8 waves, double-buffered LDS, 2-phase prefetch pipeline. Barrier is a
//     plain __syncthreads() placed AFTER the MFMA block (prefetch loads stay
//     in flight across compute; drained only at the iteration boundary).
//     Bijective XCD swizzle for L2 panel locality.
// ---------------------------------------------------------------------------

typedef unsigned short u16;
typedef __bf16 bf16x8 __attribute__((ext_vector_type(8)));
typedef unsigned short u16x4 __attribute__((ext_vector_type(4)));
typedef unsigned short u16x8s __attribute__((ext_vector_type(8)));
typedef float f32x4 __attribute__((ext_vector_type(4)));

typedef __attribute__((address_space(1))) void gvoid_t;
typedef __attribute__((address_space(3))) void svoid_t;

__device__ __forceinline__ u16 f2bf(float f) {
  unsigned u = __float_as_uint(f);
  u = (u + 0x7fffu + ((u >> 16) & 1u)) >> 16;  // RTN-even
  return (u16)u;
}
__device__ __forceinline__ float bf2f(u16 h) {
  return __uint_as_float(((unsigned)h) << 16);
}

__device__ __forceinline__ f32x4 mfma16(bf16x8 a, bf16x8 b, f32x4 c) {
  return __builtin_amdgcn_mfma_f32_16x16x32_bf16(a, b, c, 0, 0, 0);
}

// ---------------- prep: fp32 -> bf16 hi/lo split (same layout) -------------
__global__ __launch_bounds__(256) void split_hl_kernel(
    const float* __restrict__ in, u16* __restrict__ hi, u16* __restrict__ lo,
    int n4) {
  int i = blockIdx.x * 256 + threadIdx.x;
  if (i >= n4) return;
  float4 v = ((const float4*)in)[i];
  float vv[4] = {v.x, v.y, v.z, v.w};
  u16x4 h, l;
#pragma unroll
  for (int j = 0; j < 4; ++j) {
    u16 hh = f2bf(vv[j]);
    h[j] = hh;
    l[j] = f2bf(vv[j] - bf2f(hh));
  }
  ((u16x4*)hi)[i] = h;
  ((u16x4*)lo)[i] = l;
}

// ---------------- prep: transpose [512,4096] -> [4096,512] + split ---------
__global__ __launch_bounds__(256) void transpose_split_w(
    const float* __restrict__ in, u16* __restrict__ hi, u16* __restrict__ lo) {
  __shared__ float t[32][33];
  int d0 = blockIdx.x * 32, f0 = blockIdx.y * 32;
  int tx = threadIdx.x, ty = threadIdx.y;  // blockDim = (32,8)
#pragma unroll
  for (int r = 0; r < 4; ++r)
    t[ty + r * 8][tx] = in[(size_t)(f0 + ty + r * 8) * 4096 + d0 + tx];
  __syncthreads();
#pragma unroll
  for (int r = 0; r < 4; ++r) {
    float v = t[tx][ty + r * 8];  // = in[f0+tx][d0+ty+r*8]
    int d = d0 + ty + r * 8, f = f0 + tx;
    u16 h = f2bf(v);
    size_t idx = (size_t)d * 512 + f;
    hi[idx] = h;
    lo[idx] = f2bf(v - bf2f(h));
  }
}

// ---------------- shared LDS swizzle helpers -------------------------------
// LDS tiles [rows][32 k] bf16, XOR-swizzled at 16B-chunk granularity:
//   chunk (m,cq) stored at chunk col c' = cq ^ ((m>>1)&3)  (involution)
// so frag ds_read_b128 is <=2-way bank conflicted (free) AND staging stays
// compatible with global_load_lds's "base + lane*16" placement rule.
__device__ __forceinline__ bf16x8 ldsfrag(const u16* tile, int row, int quad) {
  int c = quad ^ ((row >> 1) & 3);
  return *(const bf16x8*)(tile + row * 32 + c * 8);
}

// ---------------- GEMM core (legacy 128x128): C[m][n] = sum_k A[m][k]B[n][k]
// 128x128 tile, BK=32, 256 threads (4 waves, each 64x64 = 4x4 frags of 16x16).
__device__ __forceinline__ void stage_tile(u16* ldsTile, const u16* g0, int ld,
                                           int wave, int lane) {
#pragma unroll
  for (int r = 0; r < 2; ++r) {
    int p = r * 256 + wave * 64 + lane;          // LDS chunk position
    int m = p >> 2;
    int cq = (p & 3) ^ ((m >> 1) & 3);           // global chunk col
    const u16* g = g0 + (size_t)m * ld + cq * 8;
    u16* l = ldsTile + (size_t)(r * 256 + wave * 64) * 8;  // wave-uniform
    __builtin_amdgcn_global_load_lds((gvoid_t*)g, (svoid_t*)l, 16, 0, 0);
  }
}

// OMODE: 0 = fp32 to C0 ; 1 = bf16 to C0 ; 2 = hi/lo bf16 to C0/C1
template <int SPLIT, int OMODE>
__global__ __launch_bounds__(256, 2) void gemm_bt(
    const u16* __restrict__ Ah, const u16* __restrict__ Al,
    const u16* __restrict__ Bh, const u16* __restrict__ Bl,
    void* __restrict__ C0, void* __restrict__ C1, int lda, int ldb, int ldc,
    int K, size_t aH, size_t aB, size_t bH, size_t bB, size_t cH, size_t cB) {
  __shared__ __align__(16) u16 lds[(SPLIT ? 4 : 2) * 4096];
  u16* lAh = lds;
  u16* lAl = SPLIT ? (lds + 4096) : lds;
  u16* lBh = lds + (SPLIT ? 8192 : 4096);
  u16* lBl = SPLIT ? (lds + 12288) : lds;

  const int zh = blockIdx.z >> 4, zb = blockIdx.z & 15;
  Ah += zh * aH + zb * aB;
  Al += zh * aH + zb * aB;
  Bh += zh * bH + zb * bB;
  Bl += zh * bH + zb * bB;
  const size_t cOff = zh * cH + zb * cB;

  const int m0 = blockIdx.y * 128, n0 = blockIdx.x * 128;
  const int tid = threadIdx.x;
  const int wave = tid >> 6, lane = tid & 63;
  const int quad = lane >> 4, l16 = lane & 15;
  const int wm = (wave >> 1) * 64, wn = (wave & 1) * 64;

  f32x4 acc[4][4] = {};

  for (int k0 = 0; k0 < K; k0 += 32) {
    stage_tile(lAh, Ah + (size_t)m0 * lda + k0, lda, wave, lane);
    if (SPLIT) stage_tile(lAl, Al + (size_t)m0 * lda + k0, lda, wave, lane);
    stage_tile(lBh, Bh + (size_t)n0 * ldb + k0, ldb, wave, lane);
    if (SPLIT) stage_tile(lBl, Bl + (size_t)n0 * ldb + k0, ldb, wave, lane);
    __syncthreads();

    bf16x8 a_h[4], a_l[4], b_h[4], b_l[4];
#pragma unroll
    for (int i = 0; i < 4; ++i) {
      a_h[i] = ldsfrag(lAh, wm + i * 16 + l16, quad);
      b_h[i] = ldsfrag(lBh, wn + i * 16 + l16, quad);
      if (SPLIT) {
        a_l[i] = ldsfrag(lAl, wm + i * 16 + l16, quad);
        b_l[i] = ldsfrag(lBl, wn + i * 16 + l16, quad);
      }
    }
#pragma unroll
    for (int i = 0; i < 4; ++i)
#pragma unroll
      for (int j = 0; j < 4; ++j) {
        acc[i][j] = mfma16(a_h[i], b_h[j], acc[i][j]);
        if (SPLIT) {
          acc[i][j] = mfma16(a_h[i], b_l[j], acc[i][j]);
          acc[i][j] = mfma16(a_l[i], b_h[j], acc[i][j]);
        }
      }
    __syncthreads();
  }

  // epilogue: C/D layout col = lane&15, row = quad*4 + reg (m89/m91 verified)
#pragma unroll
  for (int i = 0; i < 4; ++i) {
#pragma unroll
    for (int j = 0; j < 4; ++j) {
      int col = n0 + wn + j * 16 + l16;
#pragma unroll
      for (int r = 0; r < 4; ++r) {
        int row = m0 + wm + i * 16 + quad * 4 + r;
        size_t idx = cOff + (size_t)row * ldc + col;
        float v = acc[i][j][r];
        if (OMODE == 0) {
          ((float*)C0)[idx] = v;
        } else if (OMODE == 1) {
          ((u16*)C0)[idx] = f2bf(v);
        } else {
          u16 h = f2bf(v);
          ((u16*)C0)[idx] = h;
          ((u16*)C1)[idx] = f2bf(v - bf2f(h));
        }
      }
    }
  }
}

// ---------------- GEMM core (new 256x256, 8 waves, 2-phase pipeline) -------
// 256x256 tile, BK=32, 512 threads. Wave w = (w>>2, w&3) owns a 128x64
// sub-tile = acc[8][4] of 16x16 frags. LDS double-buffered:
//   per buffer: Ah[256][32] (+Al) , Bh[256][32] (+Bl)  -> 64 KiB (split)
//   2 buffers  -> 128 KiB (fits 160 KiB/CU, 1 block/CU).
// Pipeline (T3 minimum 2-phase): issue next tile's global_load_lds, compute
// current tile, then ONE __syncthreads() per K-step placed AFTER compute —
// its vmcnt(0) drain lands after the 96-MFMA block, so the prefetch loads'
// latency hides under compute instead of being drained before it.
__device__ __forceinline__ void stage256(u16* tile, const u16* g0, int ld,
                                         int tid) {
  const int wave = tid >> 6;
#pragma unroll
  for (int r = 0; r < 2; ++r) {
    int p = r * 512 + tid;                        // chunk index 0..1023
    int m = p >> 2;                               // row 0..255
    int cq = (p & 3) ^ ((m >> 1) & 3);            // global chunk col
    const u16* g = g0 + (size_t)m * ld + cq * 8;
    u16* l = tile + (size_t)(r * 512 + wave * 64) * 8;  // wave-uniform base
    __builtin_amdgcn_global_load_lds((gvoid_t*)g, (svoid_t*)l, 16, 0, 0);
  }
}

template <int SPLIT>
__device__ __forceinline__ void stage_all256(u16* buf, const u16* Ah,
                                             const u16* Al, const u16* Bh,
                                             const u16* Bl, int lda, int ldb,
                                             int m0, int n0, int k0, int tid) {
  stage256(buf, Ah + (size_t)m0 * lda + k0, lda, tid);
  if (SPLIT) stage256(buf + 8192, Al + (size_t)m0 * lda + k0, lda, tid);
  stage256(buf + (SPLIT ? 16384 : 8192), Bh + (size_t)n0 * ldb + k0, ldb, tid);
  if (SPLIT) stage256(buf + 24576, Bl + (size_t)n0 * ldb + k0, ldb, tid);
}

template <int SPLIT, int OMODE>
__global__ __launch_bounds__(512, 2) void gemm256(
    const u16* __restrict__ Ah, const u16* __restrict__ Al,
    const u16* __restrict__ Bh, const u16* __restrict__ Bl,
    void* __restrict__ C0, void* __restrict__ C1, int lda, int ldb, int ldc,
    int K, size_t aH, size_t aB, size_t bH, size_t bB, size_t cH, size_t cB) {
  constexpr int BUF = (SPLIT ? 4 : 2) * 8192;     // u16 per buffer
  __shared__ __align__(16) u16 lds[2 * BUF];

  // ---- bijective XCD swizzle: XCD k gets contiguous work chunk k ----
  const int gx = gridDim.x, gy = gridDim.y;
  const int nb = gx * gy * (int)gridDim.z;
  int orig = blockIdx.x + gx * (blockIdx.y + gy * blockIdx.z);
  int swz = orig;
  if ((nb & 7) == 0) swz = (orig & 7) * (nb >> 3) + (orig >> 3);
  const int bx = swz % gx;
  const int byz = swz / gx;
  const int by = byz % gy;
  const int bz = byz / gy;

  const int zh = bz >> 4, zb = bz & 15;
  Ah += zh * aH + zb * aB;
  Al += zh * aH + zb * aB;
  Bh += zh * bH + zb * bB;
  Bl += zh * bH + zb * bB;
  const size_t cOff = zh * cH + zb * cB;

  const int m0 = by * 256, n0 = bx * 256;
  const int tid = threadIdx.x;
  const int wave = tid >> 6, lane = tid & 63;
  const int quad = lane >> 4, l16 = lane & 15;
  const int wm = (wave >> 2) * 128, wn = (wave & 3) * 64;

  f32x4 acc[8][4] = {};

  // prologue: stage tile 0 into buffer 0, then barrier (drains vmcnt)
  stage_all256<SPLIT>(lds, Ah, Al, Bh, Bl, lda, ldb, m0, n0, 0, tid);
  __syncthreads();

  int cur = 0;
  for (int k0 = 0; k0 < K; k0 += 32) {
    // issue next tile's loads into the other buffer (overlaps with compute)
    if (k0 + 32 < K)
      stage_all256<SPLIT>(lds + (cur ^ 1) * BUF, Ah, Al, Bh, Bl, lda, ldb, m0,
                          n0, k0 + 32, tid);

    u16* lA_h = lds + cur * BUF;
    u16* lA_l = lA_h + 8192;
    u16* lB_h = lA_h + (SPLIT ? 16384 : 8192);
    u16* lB_l = lA_h + 24576;

    bf16x8 bhf[4], blf[4];
#pragma unroll
    for (int j = 0; j < 4; ++j) {
      bhf[j] = ldsfrag(lB_h, wn + j * 16 + l16, quad);
      if (SPLIT) blf[j] = ldsfrag(lB_l, wn + j * 16 + l16, quad);
    }
#pragma unroll
    for (int i = 0; i < 8; ++i) {
      bf16x8 ah = ldsfrag(lA_h, wm + i * 16 + l16, quad);
      bf16x8 al;
      if (SPLIT) al = ldsfrag(lA_l, wm + i * 16 + l16, quad);
#pragma unroll
      for (int j = 0; j < 4; ++j) {
        acc[i][j] = mfma16(ah, bhf[j], acc[i][j]);
        if (SPLIT) {
          acc[i][j] = mfma16(ah, blf[j], acc[i][j]);
          acc[i][j] = mfma16(al, bhf[j], acc[i][j]);
        }
      }
    }
    // ONE barrier per K-step, AFTER compute: drains the prefetch (which had
    // the whole MFMA block to complete) and releases buf[cur] for overwrite.
    __syncthreads();
    cur ^= 1;
  }

  // epilogue: C/D layout col = lane&15, row = quad*4 + reg
#pragma unroll
  for (int i = 0; i < 8; ++i) {
#pragma unroll
    for (int j = 0; j < 4; ++j) {
      int col = n0 + wn + j * 16 + l16;
#pragma unroll
      for (int r = 0; r < 4; ++r) {
        int row = m0 + wm + i * 16 + quad * 4 + r;
        size_t idx = cOff + (size_t)row * ldc + col;
        float v = acc[i][j][r];
        if (OMODE == 0) {
          ((float*)C0)[idx] = v;
        } else if (OMODE == 1) {
          ((u16*)C0)[idx] = f2bf(v);
        } else {
          u16 h = f2bf(v);
          ((u16*)C0)[idx] = h;
          ((u16*)C1)[idx] = f2bf(v - bf2f(h));
        }
      }
    }
  }
}

// ---------------- softmax over rows of 512 fp32 -> bf16 --------------------
__global__ __launch_bounds__(256) void softmax_rows(
    const float* __restrict__ in, u16* __restrict__ out) {
  int row = blockIdx.x * 4 + (threadIdx.x >> 6);
  int lane = threadIdx.x & 63;
  const float* p = in + (size_t)row * 512 + lane * 8;
  float4 v0 = *(const float4*)p;
  float4 v1 = *(const float4*)(p + 4);
  float v[8] = {v0.x, v0.y, v0.z, v0.w, v1.x, v1.y, v1.z, v1.w};
  float m = v[0];
#pragma unroll
  for (int i = 1; i < 8; ++i) m = fmaxf(m, v[i]);
#pragma unroll
  for (int o = 32; o > 0; o >>= 1) m = fmaxf(m, __shfl_xor(m, o));
  float s = 0.f;
#pragma unroll
  for (int i = 0; i < 8; ++i) {
    v[i] = __expf(v[i] - m);
    s += v[i];
  }
#pragma unroll
  for (int o = 32; o > 0; o >>= 1) s += __shfl_xor(s, o);
  float inv = 1.0f / s;
  u16x8s rr;
#pragma unroll
  for (int i = 0; i < 8; ++i) rr[i] = f2bf(v[i] * inv);
  *(u16x8s*)(out + (size_t)row * 512 + lane * 8) = rr;
}

// ---------------------------------------------------------------------------
extern "C" void kernel_launch(void* const* d_in, const int* in_sizes, int n_in,
                              void* d_out, int out_size, void* d_ws,
                              size_t ws_size, hipStream_t stream) {
  const float* x = (const float*)d_in[0];   // [16,512,512]  = [8192,512]
  const float* wq = (const float*)d_in[1];  // [512,4096]
  const float* wk = (const float*)d_in[2];
  const float* wv = (const float*)d_in[3];
  float* out = (float*)d_out;               // [16,512,4096]
  char* ws = (char*)d_ws;

  const size_t MB = 1024ull * 1024ull;
  u16* XHI = (u16*)(ws + 0 * MB);    // [8192,512] bf16 hi      8MB
  u16* XLO = (u16*)(ws + 8 * MB);    //                         8MB
  u16* WQH = (u16*)(ws + 16 * MB);   // wq split, orig layout   4MB
  u16* WQL = (u16*)(ws + 20 * MB);
  u16* WKH = (u16*)(ws + 24 * MB);
  u16* WKL = (u16*)(ws + 28 * MB);
  u16* WVTH = (u16*)(ws + 32 * MB);  // wv^T [4096,512]         4MB
  u16* WVTL = (u16*)(ws + 36 * MB);
  u16* MPH = (u16*)(ws + 40 * MB);   // M' = Wk Wq^T [8,512,512] 4MB
  u16* MPL = (u16*)(ws + 44 * MB);
  u16* THI = (u16*)(ws + 48 * MB);   // T = X M'^T [8,8192,512] 64MB
  u16* TLO = (u16*)(ws + 112 * MB);  //                         64MB
  u16* VT = (u16*)(ws + 176 * MB);   // V^T [4096,8192] bf16    64MB
  float* LOG = (float*)(ws + 240 * MB);  // logits [128,512,512] 128MB
  u16* P = THI;                      // probs alias T (T dead after logits)
  // total ws used: 368MB

  // --- prep ---
  split_hl_kernel<<<4096, 256, 0, stream>>>(x, XHI, XLO, 1048576);
  split_hl_kernel<<<2048, 256, 0, stream>>>(wq, WQH, WQL, 524288);
  split_hl_kernel<<<2048, 256, 0, stream>>>(wk, WKH, WKL, 524288);
  transpose_split_w<<<dim3(128, 16), dim3(32, 8), 0, stream>>>(wv, WVTH, WVTL);

  // --- M'_h = Wk_h Wq_h^T : [512,512] per head, x3 split, hi/lo out ---
  gemm_bt<1, 2><<<dim3(4, 4, 8), 256, 0, stream>>>(
      WKH, WKL, WQH, WQL, MPH, MPL, 4096, 4096, 512, 512,
      /*aH*/ 0, /*aB*/ 512, /*bH*/ 0, /*bB*/ 512, /*cH*/ 0, /*cB*/ 262144);

  // --- T_h = X M'_h^T : [8192,512] per head, x3, hi/lo out (256^2 kernel) ---
  gemm256<1, 2><<<dim3(2, 32, 8), 512, 0, stream>>>(
      XHI, XLO, MPH, MPL, THI, TLO, 512, 512, 512, 512,
      0, 0, 0, 262144, 0, 4194304);

  // --- V^T = Wv^T X^T : [4096 d, 8192 s], plain bf16 ---
  gemm_bt<0, 1><<<dim3(64, 32, 1), 256, 0, stream>>>(
      WVTH, WVTH, XHI, XHI, VT, nullptr, 512, 512, 8192, 512,
      0, 0, 0, 0, 0, 0);

  // --- logits_hb = T_h[b] X[b]^T : [512,512] per (h,b), x3, fp32 out ---
  gemm256<1, 0><<<dim3(2, 2, 128), 512, 0, stream>>>(
      THI, TLO, XHI, XLO, LOG, nullptr, 512, 512, 512, 512,
      /*aH*/ 4194304, /*aB*/ 262144, /*bH*/ 0, /*bB*/ 262144,
      /*cH*/ 4194304, /*cB*/ 262144);

  // --- P = softmax(logits) rows, bf16 (aliases THI) ---
  softmax_rows<<<16384, 256, 0, stream>>>(LOG, P);

  // --- out_hb = P_hb V_hb : [512 q, 512 d], plain bf16 -> fp32 out,
  //     written interleaved: out[(b*512+q)*4096 + h*512 + d] ---
  gemm_bt<0, 0><<<dim3(4, 4, 128), 256, 0, stream>>>(
      P, P, VT, VT, out, nullptr, 512, 8192, 4096, 512,
      /*aH*/ 4194304, /*aB*/ 262144, /*bH*/ 4194304, /*bB*/ 512,
      /*cH*/ 512, /*cB*/ 2097152);
}

// Round 3
// 512.856 us; speedup vs baseline: 1.3411x; 1.0749x over previous
//
#include <hip/hip_runtime.h>

// ---------------------------------------------------------------------------
// MultiHead_BlockAttention: out[b,s,h*512+d] = softmax(Q Kt) V  per (h,b)
//   Q = x@wq, K = x@wk, V = x@wv ; head h = cols [h*512,(h+1)*512)
// Trick: logits = X (Wq Wk^T) X^T  -> precompute M' = Wk Wq^T per head.
// Precision: bf16 hi/lo split (3 MFMAs) on the logit path; plain bf16 for V/P.
// R1: T/logits -> gemm256 (256x256 tile, 8 waves, double-buffered LDS,
//     2-phase prefetch pipeline, XCD swizzle).  551 us.
// R3: PV and VT moved to gemm256 too (PV was the new top dispatch: 107 us,
//     12% MfmaUtil, 4x panel re-read at 128^2 tiling).
// ---------------------------------------------------------------------------

typedef unsigned short u16;
typedef __bf16 bf16x8 __attribute__((ext_vector_type(8)));
typedef unsigned short u16x4 __attribute__((ext_vector_type(4)));
typedef unsigned short u16x8s __attribute__((ext_vector_type(8)));
typedef float f32x4 __attribute__((ext_vector_type(4)));

typedef __attribute__((address_space(1))) void gvoid_t;
typedef __attribute__((address_space(3))) void svoid_t;

__device__ __forceinline__ u16 f2bf(float f) {
  unsigned u = __float_as_uint(f);
  u = (u + 0x7fffu + ((u >> 16) & 1u)) >> 16;  // RTN-even
  return (u16)u;
}
__device__ __forceinline__ float bf2f(u16 h) {
  return __uint_as_float(((unsigned)h) << 16);
}

__device__ __forceinline__ f32x4 mfma16(bf16x8 a, bf16x8 b, f32x4 c) {
  return __builtin_amdgcn_mfma_f32_16x16x32_bf16(a, b, c, 0, 0, 0);
}

// ---------------- prep: fp32 -> bf16 hi/lo split (same layout) -------------
__global__ __launch_bounds__(256) void split_hl_kernel(
    const float* __restrict__ in, u16* __restrict__ hi, u16* __restrict__ lo,
    int n4) {
  int i = blockIdx.x * 256 + threadIdx.x;
  if (i >= n4) return;
  float4 v = ((const float4*)in)[i];
  float vv[4] = {v.x, v.y, v.z, v.w};
  u16x4 h, l;
#pragma unroll
  for (int j = 0; j < 4; ++j) {
    u16 hh = f2bf(vv[j]);
    h[j] = hh;
    l[j] = f2bf(vv[j] - bf2f(hh));
  }
  ((u16x4*)hi)[i] = h;
  ((u16x4*)lo)[i] = l;
}

// ---------------- prep: transpose [512,4096] -> [4096,512] + split ---------
__global__ __launch_bounds__(256) void transpose_split_w(
    const float* __restrict__ in, u16* __restrict__ hi, u16* __restrict__ lo) {
  __shared__ float t[32][33];
  int d0 = blockIdx.x * 32, f0 = blockIdx.y * 32;
  int tx = threadIdx.x, ty = threadIdx.y;  // blockDim = (32,8)
#pragma unroll
  for (int r = 0; r < 4; ++r)
    t[ty + r * 8][tx] = in[(size_t)(f0 + ty + r * 8) * 4096 + d0 + tx];
  __syncthreads();
#pragma unroll
  for (int r = 0; r < 4; ++r) {
    float v = t[tx][ty + r * 8];  // = in[f0+tx][d0+ty+r*8]
    int d = d0 + ty + r * 8, f = f0 + tx;
    u16 h = f2bf(v);
    size_t idx = (size_t)d * 512 + f;
    hi[idx] = h;
    lo[idx] = f2bf(v - bf2f(h));
  }
}

// ---------------- shared LDS swizzle helpers -------------------------------
// LDS tiles [rows][32 k] bf16, XOR-swizzled at 16B-chunk granularity:
//   chunk (m,cq) stored at chunk col c' = cq ^ ((m>>1)&3)  (involution)
// so frag ds_read_b128 is <=2-way bank conflicted (free) AND staging stays
// compatible with global_load_lds's "base + lane*16" placement rule.
__device__ __forceinline__ bf16x8 ldsfrag(const u16* tile, int row, int quad) {
  int c = quad ^ ((row >> 1) & 3);
  return *(const bf16x8*)(tile + row * 32 + c * 8);
}

// ---------------- GEMM core (legacy 128x128): C[m][n] = sum_k A[m][k]B[n][k]
// 128x128 tile, BK=32, 256 threads (4 waves, each 64x64 = 4x4 frags of 16x16).
__device__ __forceinline__ void stage_tile(u16* ldsTile, const u16* g0, int ld,
                                           int wave, int lane) {
#pragma unroll
  for (int r = 0; r < 2; ++r) {
    int p = r * 256 + wave * 64 + lane;          // LDS chunk position
    int m = p >> 2;
    int cq = (p & 3) ^ ((m >> 1) & 3);           // global chunk col
    const u16* g = g0 + (size_t)m * ld + cq * 8;
    u16* l = ldsTile + (size_t)(r * 256 + wave * 64) * 8;  // wave-uniform
    __builtin_amdgcn_global_load_lds((gvoid_t*)g, (svoid_t*)l, 16, 0, 0);
  }
}

// OMODE: 0 = fp32 to C0 ; 1 = bf16 to C0 ; 2 = hi/lo bf16 to C0/C1
template <int SPLIT, int OMODE>
__global__ __launch_bounds__(256, 2) void gemm_bt(
    const u16* __restrict__ Ah, const u16* __restrict__ Al,
    const u16* __restrict__ Bh, const u16* __restrict__ Bl,
    void* __restrict__ C0, void* __restrict__ C1, int lda, int ldb, int ldc,
    int K, size_t aH, size_t aB, size_t bH, size_t bB, size_t cH, size_t cB) {
  __shared__ __align__(16) u16 lds[(SPLIT ? 4 : 2) * 4096];
  u16* lAh = lds;
  u16* lAl = SPLIT ? (lds + 4096) : lds;
  u16* lBh = lds + (SPLIT ? 8192 : 4096);
  u16* lBl = SPLIT ? (lds + 12288) : lds;

  const int zh = blockIdx.z >> 4, zb = blockIdx.z & 15;
  Ah += zh * aH + zb * aB;
  Al += zh * aH + zb * aB;
  Bh += zh * bH + zb * bB;
  Bl += zh * bH + zb * bB;
  const size_t cOff = zh * cH + zb * cB;

  const int m0 = blockIdx.y * 128, n0 = blockIdx.x * 128;
  const int tid = threadIdx.x;
  const int wave = tid >> 6, lane = tid & 63;
  const int quad = lane >> 4, l16 = lane & 15;
  const int wm = (wave >> 1) * 64, wn = (wave & 1) * 64;

  f32x4 acc[4][4] = {};

  for (int k0 = 0; k0 < K; k0 += 32) {
    stage_tile(lAh, Ah + (size_t)m0 * lda + k0, lda, wave, lane);
    if (SPLIT) stage_tile(lAl, Al + (size_t)m0 * lda + k0, lda, wave, lane);
    stage_tile(lBh, Bh + (size_t)n0 * ldb + k0, ldb, wave, lane);
    if (SPLIT) stage_tile(lBl, Bl + (size_t)n0 * ldb + k0, ldb, wave, lane);
    __syncthreads();

    bf16x8 a_h[4], a_l[4], b_h[4], b_l[4];
#pragma unroll
    for (int i = 0; i < 4; ++i) {
      a_h[i] = ldsfrag(lAh, wm + i * 16 + l16, quad);
      b_h[i] = ldsfrag(lBh, wn + i * 16 + l16, quad);
      if (SPLIT) {
        a_l[i] = ldsfrag(lAl, wm + i * 16 + l16, quad);
        b_l[i] = ldsfrag(lBl, wn + i * 16 + l16, quad);
      }
    }
#pragma unroll
    for (int i = 0; i < 4; ++i)
#pragma unroll
      for (int j = 0; j < 4; ++j) {
        acc[i][j] = mfma16(a_h[i], b_h[j], acc[i][j]);
        if (SPLIT) {
          acc[i][j] = mfma16(a_h[i], b_l[j], acc[i][j]);
          acc[i][j] = mfma16(a_l[i], b_h[j], acc[i][j]);
        }
      }
    __syncthreads();
  }

  // epilogue: C/D layout col = lane&15, row = quad*4 + reg (m89/m91 verified)
#pragma unroll
  for (int i = 0; i < 4; ++i) {
#pragma unroll
    for (int j = 0; j < 4; ++j) {
      int col = n0 + wn + j * 16 + l16;
#pragma unroll
      for (int r = 0; r < 4; ++r) {
        int row = m0 + wm + i * 16 + quad * 4 + r;
        size_t idx = cOff + (size_t)row * ldc + col;
        float v = acc[i][j][r];
        if (OMODE == 0) {
          ((float*)C0)[idx] = v;
        } else if (OMODE == 1) {
          ((u16*)C0)[idx] = f2bf(v);
        } else {
          u16 h = f2bf(v);
          ((u16*)C0)[idx] = h;
          ((u16*)C1)[idx] = f2bf(v - bf2f(h));
        }
      }
    }
  }
}

// ---------------- GEMM core (256x256, 8 waves, 2-phase pipeline) -----------
// 256x256 tile, BK=32, 512 threads. Wave w = (w>>2, w&3) owns a 128x64
// sub-tile = acc[8][4] of 16x16 frags. LDS double-buffered:
//   per buffer: Ah[256][32] (+Al) , Bh[256][32] (+Bl)
//   split: 2x64 KiB = 128 KiB (1 block/CU); non-split: 2x32 KiB = 64 KiB.
// Pipeline (T3 minimum 2-phase): issue next tile's global_load_lds, compute
// current tile, then ONE __syncthreads() per K-step placed AFTER compute —
// its vmcnt(0) drain lands after the MFMA block, so the prefetch loads'
// latency hides under compute instead of being drained before it.
__device__ __forceinline__ void stage256(u16* tile, const u16* g0, int ld,
                                         int tid) {
  const int wave = tid >> 6;
#pragma unroll
  for (int r = 0; r < 2; ++r) {
    int p = r * 512 + tid;                        // chunk index 0..1023
    int m = p >> 2;                               // row 0..255
    int cq = (p & 3) ^ ((m >> 1) & 3);            // global chunk col
    const u16* g = g0 + (size_t)m * ld + cq * 8;
    u16* l = tile + (size_t)(r * 512 + wave * 64) * 8;  // wave-uniform base
    __builtin_amdgcn_global_load_lds((gvoid_t*)g, (svoid_t*)l, 16, 0, 0);
  }
}

template <int SPLIT>
__device__ __forceinline__ void stage_all256(u16* buf, const u16* Ah,
                                             const u16* Al, const u16* Bh,
                                             const u16* Bl, int lda, int ldb,
                                             int m0, int n0, int k0, int tid) {
  stage256(buf, Ah + (size_t)m0 * lda + k0, lda, tid);
  if (SPLIT) stage256(buf + 8192, Al + (size_t)m0 * lda + k0, lda, tid);
  stage256(buf + (SPLIT ? 16384 : 8192), Bh + (size_t)n0 * ldb + k0, ldb, tid);
  if (SPLIT) stage256(buf + 24576, Bl + (size_t)n0 * ldb + k0, ldb, tid);
}

template <int SPLIT, int OMODE>
__global__ __launch_bounds__(512, 2) void gemm256(
    const u16* __restrict__ Ah, const u16* __restrict__ Al,
    const u16* __restrict__ Bh, const u16* __restrict__ Bl,
    void* __restrict__ C0, void* __restrict__ C1, int lda, int ldb, int ldc,
    int K, size_t aH, size_t aB, size_t bH, size_t bB, size_t cH, size_t cB) {
  constexpr int BUF = (SPLIT ? 4 : 2) * 8192;     // u16 per buffer
  __shared__ __align__(16) u16 lds[2 * BUF];

  // ---- bijective XCD swizzle: XCD k gets contiguous work chunk k ----
  const int gx = gridDim.x, gy = gridDim.y;
  const int nb = gx * gy * (int)gridDim.z;
  int orig = blockIdx.x + gx * (blockIdx.y + gy * blockIdx.z);
  int swz = orig;
  if ((nb & 7) == 0) swz = (orig & 7) * (nb >> 3) + (orig >> 3);
  const int bx = swz % gx;
  const int byz = swz / gx;
  const int by = byz % gy;
  const int bz = byz / gy;

  const int zh = bz >> 4, zb = bz & 15;
  Ah += zh * aH + zb * aB;
  Al += zh * aH + zb * aB;
  Bh += zh * bH + zb * bB;
  Bl += zh * bH + zb * bB;
  const size_t cOff = zh * cH + zb * cB;

  const int m0 = by * 256, n0 = bx * 256;
  const int tid = threadIdx.x;
  const int wave = tid >> 6, lane = tid & 63;
  const int quad = lane >> 4, l16 = lane & 15;
  const int wm = (wave >> 2) * 128, wn = (wave & 3) * 64;

  f32x4 acc[8][4] = {};

  // prologue: stage tile 0 into buffer 0, then barrier (drains vmcnt)
  stage_all256<SPLIT>(lds, Ah, Al, Bh, Bl, lda, ldb, m0, n0, 0, tid);
  __syncthreads();

  int cur = 0;
  for (int k0 = 0; k0 < K; k0 += 32) {
    // issue next tile's loads into the other buffer (overlaps with compute)
    if (k0 + 32 < K)
      stage_all256<SPLIT>(lds + (cur ^ 1) * BUF, Ah, Al, Bh, Bl, lda, ldb, m0,
                          n0, k0 + 32, tid);

    u16* lA_h = lds + cur * BUF;
    u16* lA_l = lA_h + 8192;
    u16* lB_h = lA_h + (SPLIT ? 16384 : 8192);
    u16* lB_l = lA_h + 24576;

    bf16x8 bhf[4], blf[4];
#pragma unroll
    for (int j = 0; j < 4; ++j) {
      bhf[j] = ldsfrag(lB_h, wn + j * 16 + l16, quad);
      if (SPLIT) blf[j] = ldsfrag(lB_l, wn + j * 16 + l16, quad);
    }
#pragma unroll
    for (int i = 0; i < 8; ++i) {
      bf16x8 ah = ldsfrag(lA_h, wm + i * 16 + l16, quad);
      bf16x8 al;
      if (SPLIT) al = ldsfrag(lA_l, wm + i * 16 + l16, quad);
#pragma unroll
      for (int j = 0; j < 4; ++j) {
        acc[i][j] = mfma16(ah, bhf[j], acc[i][j]);
        if (SPLIT) {
          acc[i][j] = mfma16(ah, blf[j], acc[i][j]);
          acc[i][j] = mfma16(al, bhf[j], acc[i][j]);
        }
      }
    }
    // ONE barrier per K-step, AFTER compute: drains the prefetch (which had
    // the whole MFMA block to complete) and releases buf[cur] for overwrite.
    __syncthreads();
    cur ^= 1;
  }

  // epilogue: C/D layout col = lane&15, row = quad*4 + reg
#pragma unroll
  for (int i = 0; i < 8; ++i) {
#pragma unroll
    for (int j = 0; j < 4; ++j) {
      int col = n0 + wn + j * 16 + l16;
#pragma unroll
      for (int r = 0; r < 4; ++r) {
        int row = m0 + wm + i * 16 + quad * 4 + r;
        size_t idx = cOff + (size_t)row * ldc + col;
        float v = acc[i][j][r];
        if (OMODE == 0) {
          ((float*)C0)[idx] = v;
        } else if (OMODE == 1) {
          ((u16*)C0)[idx] = f2bf(v);
        } else {
          u16 h = f2bf(v);
          ((u16*)C0)[idx] = h;
          ((u16*)C1)[idx] = f2bf(v - bf2f(h));
        }
      }
    }
  }
}

// ---------------- softmax over rows of 512 fp32 -> bf16 --------------------
__global__ __launch_bounds__(256) void softmax_rows(
    const float* __restrict__ in, u16* __restrict__ out) {
  int row = blockIdx.x * 4 + (threadIdx.x >> 6);
  int lane = threadIdx.x & 63;
  const float* p = in + (size_t)row * 512 + lane * 8;
  float4 v0 = *(const float4*)p;
  float4 v1 = *(const float4*)(p + 4);
  float v[8] = {v0.x, v0.y, v0.z, v0.w, v1.x, v1.y, v1.z, v1.w};
  float m = v[0];
#pragma unroll
  for (int i = 1; i < 8; ++i) m = fmaxf(m, v[i]);
#pragma unroll
  for (int o = 32; o > 0; o >>= 1) m = fmaxf(m, __shfl_xor(m, o));
  float s = 0.f;
#pragma unroll
  for (int i = 0; i < 8; ++i) {
    v[i] = __expf(v[i] - m);
    s += v[i];
  }
#pragma unroll
  for (int o = 32; o > 0; o >>= 1) s += __shfl_xor(s, o);
  float inv = 1.0f / s;
  u16x8s rr;
#pragma unroll
  for (int i = 0; i < 8; ++i) rr[i] = f2bf(v[i] * inv);
  *(u16x8s*)(out + (size_t)row * 512 + lane * 8) = rr;
}

// ---------------------------------------------------------------------------
extern "C" void kernel_launch(void* const* d_in, const int* in_sizes, int n_in,
                              void* d_out, int out_size, void* d_ws,
                              size_t ws_size, hipStream_t stream) {
  const float* x = (const float*)d_in[0];   // [16,512,512]  = [8192,512]
  const float* wq = (const float*)d_in[1];  // [512,4096]
  const float* wk = (const float*)d_in[2];
  const float* wv = (const float*)d_in[3];
  float* out = (float*)d_out;               // [16,512,4096]
  char* ws = (char*)d_ws;

  const size_t MB = 1024ull * 1024ull;
  u16* XHI = (u16*)(ws + 0 * MB);    // [8192,512] bf16 hi      8MB
  u16* XLO = (u16*)(ws + 8 * MB);    //                         8MB
  u16* WQH = (u16*)(ws + 16 * MB);   // wq split, orig layout   4MB
  u16* WQL = (u16*)(ws + 20 * MB);
  u16* WKH = (u16*)(ws + 24 * MB);
  u16* WKL = (u16*)(ws + 28 * MB);
  u16* WVTH = (u16*)(ws + 32 * MB);  // wv^T [4096,512]         4MB
  u16* WVTL = (u16*)(ws + 36 * MB);
  u16* MPH = (u16*)(ws + 40 * MB);   // M' = Wk Wq^T [8,512,512] 4MB
  u16* MPL = (u16*)(ws + 44 * MB);
  u16* THI = (u16*)(ws + 48 * MB);   // T = X M'^T [8,8192,512] 64MB
  u16* TLO = (u16*)(ws + 112 * MB);  //                         64MB
  u16* VT = (u16*)(ws + 176 * MB);   // V^T [4096,8192] bf16    64MB
  float* LOG = (float*)(ws + 240 * MB);  // logits [128,512,512] 128MB
  u16* P = THI;                      // probs alias T (T dead after logits)
  // total ws used: 368MB

  // --- prep ---
  split_hl_kernel<<<4096, 256, 0, stream>>>(x, XHI, XLO, 1048576);
  split_hl_kernel<<<2048, 256, 0, stream>>>(wq, WQH, WQL, 524288);
  split_hl_kernel<<<2048, 256, 0, stream>>>(wk, WKH, WKL, 524288);
  transpose_split_w<<<dim3(128, 16), dim3(32, 8), 0, stream>>>(wv, WVTH, WVTL);

  // --- M'_h = Wk_h Wq_h^T : [512,512] per head, x3 split, hi/lo out ---
  // (stays on the 128^2 kernel: at 256^2 it would be only 32 blocks)
  gemm_bt<1, 2><<<dim3(4, 4, 8), 256, 0, stream>>>(
      WKH, WKL, WQH, WQL, MPH, MPL, 4096, 4096, 512, 512,
      /*aH*/ 0, /*aB*/ 512, /*bH*/ 0, /*bB*/ 512, /*cH*/ 0, /*cB*/ 262144);

  // --- T_h = X M'_h^T : [8192,512] per head, x3, hi/lo out ---
  gemm256<1, 2><<<dim3(2, 32, 8), 512, 0, stream>>>(
      XHI, XLO, MPH, MPL, THI, TLO, 512, 512, 512, 512,
      0, 0, 0, 262144, 0, 4194304);

  // --- V^T = Wv^T X^T : [4096 d, 8192 s], plain bf16 (256^2 kernel) ---
  gemm256<0, 1><<<dim3(32, 16, 1), 512, 0, stream>>>(
      WVTH, WVTH, XHI, XHI, VT, nullptr, 512, 512, 8192, 512,
      0, 0, 0, 0, 0, 0);

  // --- logits_hb = T_h[b] X[b]^T : [512,512] per (h,b), x3, fp32 out ---
  gemm256<1, 0><<<dim3(2, 2, 128), 512, 0, stream>>>(
      THI, TLO, XHI, XLO, LOG, nullptr, 512, 512, 512, 512,
      /*aH*/ 4194304, /*aB*/ 262144, /*bH*/ 0, /*bB*/ 262144,
      /*cH*/ 4194304, /*cB*/ 262144);

  // --- P = softmax(logits) rows, bf16 (aliases THI) ---
  softmax_rows<<<16384, 256, 0, stream>>>(LOG, P);

  // --- out_hb = P_hb V_hb : [512 q, 512 d], plain bf16 -> fp32 out,
  //     written interleaved: out[(b*512+q)*4096 + h*512 + d] (256^2 kernel) ---
  gemm256<0, 0><<<dim3(2, 2, 128), 512, 0, stream>>>(
      P, P, VT, VT, out, nullptr, 512, 8192, 4096, 512,
      /*aH*/ 4194304, /*aB*/ 262144, /*bH*/ 4194304, /*bB*/ 512,
      /*cH*/ 512, /*cB*/ 2097152);
}